// Round 6
// baseline (251.207 us; speedup 1.0000x reference)
//
#include <hip/hip_runtime.h>

#define QN 8192
#define CCH 64
#define NROW 65536   // B*Q*4
#define MR 64        // rows per block in k_fused
#define NBLK (NROW / MR)   // 1024
#define H0S 264      // LDS f16 stride for h0/h1 staging

typedef _Float16 f16x8 __attribute__((ext_vector_type(8)));
typedef _Float16 f16x4 __attribute__((ext_vector_type(4)));
typedef float f32x4 __attribute__((ext_vector_type(4)));

__device__ __forceinline__ float gelu_f(float x) {
    float x2 = x * x;
    float tt = fmaf(0.044715f, x2, 1.0f);
    float e = __expf(1.5957691216f * x * tt);
    float r = __builtin_amdgcn_rcpf(1.0f + e);
    return x - x * r;
}

// ---------------- K_pre: conv (blocks 0..2177) + prep (2178..2433) + cvt (2434..4417)
__global__ __launch_bounds__(256) void k_pre(const float* __restrict__ inp,
                                             const float* __restrict__ ew,
                                             const float* __restrict__ eb,
                                             const float* __restrict__ coord,
                                             const float* __restrict__ scale,
                                             const float* __restrict__ sw0,
                                             const float* __restrict__ sb0,
                                             const float* __restrict__ sw1,
                                             const float* __restrict__ sb1,
                                             const float* __restrict__ iw1,
                                             const float* __restrict__ iw2,
                                             const float* __restrict__ ib2,
                                             float* __restrict__ featpad,
                                             float4* __restrict__ mlp_in,
                                             int2* __restrict__ ihiw,
                                             float* __restrict__ scoreg,
                                             _Float16* __restrict__ w1tp,
                                             _Float16* __restrict__ w2tp,
                                             float* __restrict__ b2p) {
    const int bb = blockIdx.x;
    const int tt0 = threadIdx.x;
    if (bb < 2178) {
        // conv3x3 (3->64) + bias, zero-padded channel-LAST (B,66,66,64)
        __shared__ float s_ew[1728];
        for (int i = tt0; i < 1728; i += 256) s_ew[i] = ew[i];
        __syncthreads();
        int idx = bb * 256 + tt0;
        const int total = 2 * 66 * 66 * CCH;
        if (idx >= total) return;
        int o = idx & 63; int pix = idx >> 6;
        int xx = pix % 66; int t2 = pix / 66;
        int yy = t2 % 66;  int b = t2 / 66;
        int y = yy - 1, x = xx - 1;
        float acc = 0.0f;
        if (y >= 0 && y < 64 && x >= 0 && x < 64) {
            acc = eb[o];
            for (int i = 0; i < 3; ++i) {
                const float* ip = inp + ((b * 3 + i) * 64) * 64;
                const float* wp = s_ew + (o * 3 + i) * 9;
                #pragma unroll
                for (int ky = 0; ky < 3; ++ky) {
                    int sy = y + ky - 1;
                    if (sy < 0 || sy > 63) continue;
                    #pragma unroll
                    for (int kx = 0; kx < 3; ++kx) {
                        int sx = x + kx - 1;
                        if (sx < 0 || sx > 63) continue;
                        acc += ip[sy * 64 + sx] * wp[ky * 3 + kx];
                    }
                }
            }
        }
        featpad[idx] = acc;
    } else if (bb < 2434) {
        // per-row prep + score MLP (2->256->1) folded with sb1
        int row = (bb - 2178) * 256 + tt0;
        int v = row & 3;
        int bq = row >> 2;
        int b = bq >> 13;
        float c0 = coord[bq * 2 + 0], c1 = coord[bq * 2 + 1];
        float s0 = scale[bq * 2 + 0], s1 = scale[bq * 2 + 1];
        float s00 = scale[(b * QN) * 2 + 0];
        float s01 = scale[(b * QN) * 2 + 1];
        float rx = (1.0f - s00) / 63.0f;
        float ry = (1.0f - s01) / 63.0f;
        float vx = (v & 2) ? 1.0f : -1.0f;
        float vy = (v & 1) ? 1.0f : -1.0f;
        float cc0 = c0 + vx * rx + 1e-6f;
        float cc1 = c1 + vy * ry + 1e-6f;
        cc0 = fminf(fmaxf(cc0, -1.0f + 1e-6f), 1.0f - 1e-6f);
        cc1 = fminf(fmaxf(cc1, -1.0f + 1e-6f), 1.0f - 1e-6f);
        int ih = (int)rintf((cc0 + 1.0f) * 32.0f - 0.5f);
        int iw = (int)rintf((cc1 + 1.0f) * 32.0f - 0.5f);
        ih = min(max(ih, 0), 63);
        iw = min(max(iw, 0), 63);
        float ck0 = (2.0f * (float)ih + 1.0f) / 64.0f - 1.0f;
        float ck1 = (2.0f * (float)iw + 1.0f) / 64.0f - 1.0f;
        float rel0 = (c0 - ck0) * 64.0f;
        float rel1 = (c1 - ck1) * 64.0f;
        mlp_in[row] = make_float4(rel0, rel1, s0 * 64.0f, s1 * 64.0f);
        ihiw[row] = make_int2(ih, iw);
        float sc = sb1[0];
        #pragma unroll 4
        for (int t2 = 0; t2 < 256; ++t2) {
            float h = gelu_f(fmaf(rel0, sw0[t2], fmaf(rel1, sw0[256 + t2], sb0[t2])));
            sc = fmaf(h, sw1[t2], sc);
        }
        scoreg[row] = sc;
    } else {
        // weight convert to LANE-MAJOR fragment layouts (coalesced loads in k_fused).
        int idx = (bb - 2434) * 256 + tt0;
        if (idx < 442368) {
            int j = idx & 7, ln = (idx >> 3) & 63, kf = (idx >> 9) & 7, tl = idx >> 12;
            int np = tl * 16 + (ln & 15);
            int kk = kf * 32 + (ln >> 4) * 8 + j;
            int k_out = np / 576;
            int rem = np - 576 * k_out;
            int tap = rem >> 6, cch = rem & 63;
            int n = (cch * 9 + tap) * 3 + k_out;
            w2tp[idx] = (_Float16)iw2[kk * 1728 + n];
            if (kf == 0 && j == 0 && (ln >> 4) == 0) b2p[np] = ib2[n];
        } else {
            int i2 = idx - 442368;
            int j = i2 & 7, ln = (i2 >> 3) & 63, kf = (i2 >> 9) & 7, ct = i2 >> 12;
            int col = ct * 16 + (ln & 15);
            int kk = kf * 32 + (ln >> 4) * 8 + j;
            w1tp[i2] = (_Float16)iw1[kk * 256 + col];
        }
    }
}

// ---------------- K_fused: h0 -> h1 (MFMA) -> GEMM3 + value-dot -> +score -> weight MLP
__global__ __launch_bounds__(256, 2) void k_fused(const float* __restrict__ featpad,
                                                  const float4* __restrict__ mlp_in,
                                                  const int2* __restrict__ ihiw,
                                                  const float* __restrict__ iw0,
                                                  const float* __restrict__ ib0,
                                                  const _Float16* __restrict__ w1tp,
                                                  const float* __restrict__ ib1,
                                                  const _Float16* __restrict__ w2tp,
                                                  const float* __restrict__ b2p,
                                                  const float* __restrict__ scoreg,
                                                  const float* __restrict__ ww0,
                                                  const float* __restrict__ wb0,
                                                  const float* __restrict__ ww1,
                                                  const float* __restrict__ wb1,
                                                  float* __restrict__ out) {
    // pool: s_valT [576][64] f16 row-XOR swizzled = 73728 B; aliased by s_h0/h1 [64][264] f16
    __shared__ __align__(16) char pool[576 * 64 * 2];
    _Float16* s_h0   = (_Float16*)pool;
    _Float16* s_valT = (_Float16*)pool;
    __shared__ float4 s_min[MR];
    __shared__ int    s_base[MR];
    __shared__ int    s_dtab[9];
    __shared__ float  s_pred[MR][3];
    __shared__ float  s_score[MR];
    __shared__ float  s_wred[48][4];

    const int t = threadIdx.x;
    const int wave = t >> 6, lane = t & 63, quad = lane >> 4, l15 = lane & 15;
    const int rowbase = blockIdx.x * MR;

    if (t < MR) {
        int row = rowbase + t;
        s_min[t] = mlp_in[row];
        s_score[t] = scoreg[row];
        int b = row >> 15;
        int2 p = ihiw[row];
        s_base[t] = ((b * 66 + p.x) * 66 + p.y) * 64;
    }
    if (t < 9) { int di = t / 3; s_dtab[t] = (di * 66 + (t - 3 * di)) * 64; }
    if (t < MR * 3) s_pred[t / 3][t % 3] = 0.0f;
    __syncthreads();

    // ---- h0 (4->256) fp32 VALU -> LDS f16 ([64][264])
    {
        float w0 = iw0[t], w1 = iw0[256 + t], w2 = iw0[512 + t], w3 = iw0[768 + t];
        float bb = ib0[t];
        #pragma unroll 4
        for (int r = 0; r < MR; ++r) {
            float4 m = s_min[r];
            s_h0[r * H0S + t] =
                (_Float16)gelu_f(fmaf(m.x, w0, fmaf(m.y, w1, fmaf(m.z, w2, fmaf(m.w, w3, bb)))));
        }
    }
    __syncthreads();

    f16x8 a[4][8];   // A fragments: 4 row-tiles x 8 k-frags (whole 64xK for this wave)
    #pragma unroll
    for (int rt = 0; rt < 4; ++rt)
        #pragma unroll
        for (int kf = 0; kf < 8; ++kf)
            a[rt][kf] = *(const f16x8*)(s_h0 + (rt * 16 + l15) * H0S + kf * 32 + quad * 8);
    __syncthreads();   // all h0 reads done before in-place h1 writes

    // ---- h1 (256->256) MFMA; wave owns col-tiles wave*4..wave*4+3, all 64 rows
    #pragma unroll 1
    for (int c = 0; c < 4; ++c) {
        int ct = wave * 4 + c;
        f16x8 bf[8];
        #pragma unroll
        for (int kf = 0; kf < 8; ++kf)
            bf[kf] = *(const f16x8*)(w1tp + ((ct * 8 + kf) * 64 + lane) * 8);
        f32x4 acc[4] = {{0.f,0.f,0.f,0.f},{0.f,0.f,0.f,0.f},{0.f,0.f,0.f,0.f},{0.f,0.f,0.f,0.f}};
        #pragma unroll
        for (int kf = 0; kf < 8; ++kf)
            #pragma unroll
            for (int rt = 0; rt < 4; ++rt)
                acc[rt] = __builtin_amdgcn_mfma_f32_16x16x32_f16(a[rt][kf], bf[kf], acc[rt], 0, 0, 0);
        int col = ct * 16 + l15;
        float bias = ib1[col];
        #pragma unroll
        for (int rt = 0; rt < 4; ++rt)
            #pragma unroll
            for (int reg = 0; reg < 4; ++reg)
                s_h0[(rt * 16 + quad * 4 + reg) * H0S + col] = (_Float16)gelu_f(acc[rt][reg] + bias);
    }
    __syncthreads();

    // ---- A3 fragments from LDS h1 (reuse a[])
    #pragma unroll
    for (int rt = 0; rt < 4; ++rt)
        #pragma unroll
        for (int kf = 0; kf < 8; ++kf)
            a[rt][kf] = *(const f16x8*)(s_h0 + (rt * 16 + l15) * H0S + kf * 32 + quad * 8);
    __syncthreads();   // h1 reads done; region becomes s_valT

    // ---- preload first B half-tile (latency hidden under gather)
    const int tbase = wave * 27;
    f16x8 bfX[4], bfY[4];
    {
        const _Float16* wp = w2tp + (size_t)(tbase * 8) * 512 + lane * 8;
        #pragma unroll
        for (int kf = 0; kf < 4; ++kf) bfX[kf] = *(const f16x8*)(wp + kf * 512);
    }

    // ---- value gather: COALESCED. Each wave-load = 4 (row,tap) segments x 16 lanes x float4.
    // p = (row,tap) pair index; r = p/9 (magic 7283), tap = p - 9r.
    // LDS val layout: addr = cfp*64 + (row ^ ((cfp&15)<<2))  (swizzle multiple of 4 -> b64 reads ok)
    #pragma unroll 1
    for (int it = 0; it < 36; ++it) {
        int p = (wave * 36 + it) * 4 + quad;
        int r = (p * 7283) >> 16;
        int tap = p - 9 * r;
        const float4 v = *(const float4*)(featpad + s_base[r] + s_dtab[tap] + l15 * 4);
        int cfp0 = tap * 64 + l15 * 4;
        int g = (cfp0 & 15) << 2;   // constant across j=0..3 (low2 of cfp don't enter &15>>... bits2-3 fixed)
        _Float16* wp = s_valT + cfp0 * 64 + (r ^ ((cfp0 & 12) << 2));
        // note: (cfp&15)<<2 varies with j in bits 2-3; recompute per element:
        s_valT[(cfp0 + 0) * 64 + (r ^ (((cfp0 + 0) & 15) << 2))] = (_Float16)v.x;
        s_valT[(cfp0 + 1) * 64 + (r ^ (((cfp0 + 1) & 15) << 2))] = (_Float16)v.y;
        s_valT[(cfp0 + 2) * 64 + (r ^ (((cfp0 + 2) & 15) << 2))] = (_Float16)v.z;
        s_valT[(cfp0 + 3) * 64 + (r ^ (((cfp0 + 3) & 15) << 2))] = (_Float16)v.w;
        (void)g; (void)wp;
    }
    __syncthreads();

    // ---- GEMM3 (256->1728 permuted cols) + fused value-dot
    // wave owns 27 col-tiles; single accumulator + flush at the (wave-uniform) kt boundary
    const int kt0 = tbase / 36;
    int bsplit = (kt0 + 1) * 36 - tbase; if (bsplit > 27) bsplit = 27;
    const int ktB = (tbase + 26) / 36;

    float pA[4][4];
    #pragma unroll
    for (int rt = 0; rt < 4; ++rt)
        #pragma unroll
        for (int rg = 0; rg < 4; ++rg) pA[rt][rg] = 0.f;

    float bv;
    #pragma unroll 1
    for (int i = 0; i < 27; ++i) {
        int ti = tbase + i;
        {   // load current tile's second B half (Y) + bias
            const _Float16* wp = w2tp + (size_t)(ti * 8 + 4) * 512 + lane * 8;
            #pragma unroll
            for (int kf = 0; kf < 4; ++kf) bfY[kf] = *(const f16x8*)(wp + kf * 512);
            bv = b2p[ti * 16 + l15];
        }
        f32x4 acc[4] = {{0.f,0.f,0.f,0.f},{0.f,0.f,0.f,0.f},{0.f,0.f,0.f,0.f},{0.f,0.f,0.f,0.f}};
        #pragma unroll
        for (int kf = 0; kf < 4; ++kf)
            #pragma unroll
            for (int rt = 0; rt < 4; ++rt)
                acc[rt] = __builtin_amdgcn_mfma_f32_16x16x32_f16(a[rt][kf], bfX[kf], acc[rt], 0, 0, 0);
        if (i < 26) {   // prefetch next tile's first B half (X)
            const _Float16* wp = w2tp + (size_t)((ti + 1) * 8) * 512 + lane * 8;
            #pragma unroll
            for (int kf = 0; kf < 4; ++kf) bfX[kf] = *(const f16x8*)(wp + kf * 512);
        }
        #pragma unroll
        for (int kf = 0; kf < 4; ++kf)
            #pragma unroll
            for (int rt = 0; rt < 4; ++rt)
                acc[rt] = __builtin_amdgcn_mfma_f32_16x16x32_f16(a[rt][kf + 4], bfY[kf], acc[rt], 0, 0, 0);
        // epilogue: fold (acc + bias) * val into pA
        int cf36 = ti - (ti / 36) * 36;
        int cfp = cf36 * 16 + l15;
        int g = (cfp & 15) << 2;
        const _Float16* vbase = s_valT + cfp * 64;
        #pragma unroll
        for (int rt = 0; rt < 4; ++rt) {
            f16x4 vv = *(const f16x4*)(vbase + ((rt * 16 + quad * 4) ^ g));
            #pragma unroll
            for (int rg = 0; rg < 4; ++rg) {
                float s = acc[rt][rg] + bv;
                pA[rt][rg] = fmaf(s, (float)vv[rg], pA[rt][rg]);
            }
        }
        if (i == bsplit - 1) {   // wave-uniform flush into s_pred[*][kt0]
            #pragma unroll
            for (int rt = 0; rt < 4; ++rt)
                #pragma unroll
                for (int rg = 0; rg < 4; ++rg) {
                    float x = pA[rt][rg];
                    #pragma unroll
                    for (int m = 1; m < 16; m <<= 1) x += __shfl_xor(x, m, 64);
                    if (l15 == 0) atomicAdd(&s_pred[rt * 16 + quad * 4 + rg][kt0], x);
                    pA[rt][rg] = 0.f;
                }
        }
    }
    // final flush into s_pred[*][ktB]
    #pragma unroll
    for (int rt = 0; rt < 4; ++rt)
        #pragma unroll
        for (int rg = 0; rg < 4; ++rg) {
            float x = pA[rt][rg];
            #pragma unroll
            for (int m = 1; m < 16; m <<= 1) x += __shfl_xor(x, m, 64);
            if (l15 == 0) atomicAdd(&s_pred[rt * 16 + quad * 4 + rg][ktB], x);
        }
    __syncthreads();

    // ---- fused weight MLP (4->256->1): 16 bq x 3 k outputs, 4 sub-threads each
    if (t < 192) {
        int o = t >> 2, sub = t & 3;          // o = bql*3 + k
        int bql = o / 3, k = o - 3 * bql;
        float x0 = s_pred[bql * 4 + 0][k] + s_score[bql * 4 + 0];
        float x1 = s_pred[bql * 4 + 1][k] + s_score[bql * 4 + 1];
        float x2 = s_pred[bql * 4 + 2][k] + s_score[bql * 4 + 2];
        float x3 = s_pred[bql * 4 + 3][k] + s_score[bql * 4 + 3];
        float acc = 0.0f;
        int j0 = sub * 64;
        #pragma unroll 4
        for (int j = j0; j < j0 + 64; ++j) {
            float h = gelu_f(fmaf(x0, ww0[j], fmaf(x1, ww0[256 + j],
                          fmaf(x2, ww0[512 + j], fmaf(x3, ww0[768 + j], wb0[j])))));
            acc = fmaf(h, ww1[j], acc);
        }
        s_wred[o][sub] = acc;
    }
    __syncthreads();
    if (t < 48) {
        int bql = t / 3, k = t - 3 * bql;
        float r2 = s_wred[t][0] + s_wred[t][1] + s_wred[t][2] + s_wred[t][3] + wb1[0];
        out[(blockIdx.x * 16 + bql) * 3 + k] = r2;
    }
}

extern "C" void kernel_launch(void* const* d_in, const int* in_sizes, int n_in,
                              void* d_out, int out_size, void* d_ws, size_t ws_size,
                              hipStream_t stream) {
    const float* inp   = (const float*)d_in[0];
    const float* coord = (const float*)d_in[1];
    const float* scale = (const float*)d_in[2];
    const float* ew    = (const float*)d_in[3];
    const float* eb    = (const float*)d_in[4];
    const float* iw0   = (const float*)d_in[5];
    const float* ib0   = (const float*)d_in[6];
    const float* iw1   = (const float*)d_in[7];
    const float* ib1   = (const float*)d_in[8];
    const float* iw2   = (const float*)d_in[9];
    const float* ib2   = (const float*)d_in[10];
    const float* sw0   = (const float*)d_in[11];
    const float* sb0   = (const float*)d_in[12];
    const float* sw1   = (const float*)d_in[13];
    const float* sb1   = (const float*)d_in[14];
    const float* ww0   = (const float*)d_in[15];
    const float* wb0   = (const float*)d_in[16];
    const float* ww1   = (const float*)d_in[17];
    const float* wb1   = (const float*)d_in[18];
    float* out = (float*)d_out;

    char* ws = (char*)d_ws;
    float*     featpad = (float*)(ws + 0);           // 2,230,272
    float4*    mlp_in  = (float4*)(ws + 2230272);    // 1,048,576
    int2*      ihiw    = (int2*)(ws + 3278848);      //   524,288
    float*     scoreg  = (float*)(ws + 3803136);     //   262,144
    _Float16*  w1tp    = (_Float16*)(ws + 4065280);  //   131,072
    _Float16*  w2tp    = (_Float16*)(ws + 4196352);  //   884,736
    float*     b2p     = (float*)(ws + 5081088);     //     6,912  (end 5,088,000)

    k_pre<<<dim3(4418), dim3(256), 0, stream>>>(inp, ew, eb, coord, scale,
                                                sw0, sb0, sw1, sb1, iw1, iw2, ib2,
                                                featpad, mlp_in, ihiw, scoreg,
                                                w1tp, w2tp, b2p);
    k_fused<<<dim3(NBLK), dim3(256), 0, stream>>>(featpad, mlp_in, ihiw,
                                                  iw0, ib0, w1tp, ib1, w2tp, b2p,
                                                  scoreg, ww0, wb0, ww1, wb1, out);
}

// Round 7
// 240.406 us; speedup vs baseline: 1.0449x; 1.0449x over previous
//
#include <hip/hip_runtime.h>

#define QN 8192
#define CCH 64
#define NROW 65536   // B*Q*4
#define MR 64        // rows per block in k_fused
#define NBLK (NROW / MR)   // 1024
#define H0S 264      // LDS f16 stride for h0/h1 staging

typedef _Float16 f16x8 __attribute__((ext_vector_type(8)));
typedef _Float16 f16x4 __attribute__((ext_vector_type(4)));
typedef float f32x4 __attribute__((ext_vector_type(4)));

__device__ __forceinline__ float gelu_f(float x) {
    float x2 = x * x;
    float tt = fmaf(0.044715f, x2, 1.0f);
    float e = __expf(1.5957691216f * x * tt);
    float r = __builtin_amdgcn_rcpf(1.0f + e);
    return x - x * r;
}

// ---------------- K_pre: conv (blocks 0..2177) + prep (2178..2433) + cvt (2434..4417)
__global__ __launch_bounds__(256) void k_pre(const float* __restrict__ inp,
                                             const float* __restrict__ ew,
                                             const float* __restrict__ eb,
                                             const float* __restrict__ coord,
                                             const float* __restrict__ scale,
                                             const float* __restrict__ sw0,
                                             const float* __restrict__ sb0,
                                             const float* __restrict__ sw1,
                                             const float* __restrict__ sb1,
                                             const float* __restrict__ iw1,
                                             const float* __restrict__ iw2,
                                             const float* __restrict__ ib2,
                                             float* __restrict__ featpad,
                                             float4* __restrict__ mlp_in,
                                             int2* __restrict__ ihiw,
                                             float* __restrict__ scoreg,
                                             _Float16* __restrict__ w1tp,
                                             _Float16* __restrict__ w2tp,
                                             float* __restrict__ b2p) {
    const int bb = blockIdx.x;
    const int tt0 = threadIdx.x;
    if (bb < 2178) {
        // conv3x3 (3->64) + bias, zero-padded channel-LAST (B,66,66,64)
        __shared__ float s_ew[1728];
        for (int i = tt0; i < 1728; i += 256) s_ew[i] = ew[i];
        __syncthreads();
        int idx = bb * 256 + tt0;
        const int total = 2 * 66 * 66 * CCH;
        if (idx >= total) return;
        int o = idx & 63; int pix = idx >> 6;
        int xx = pix % 66; int t2 = pix / 66;
        int yy = t2 % 66;  int b = t2 / 66;
        int y = yy - 1, x = xx - 1;
        float acc = 0.0f;
        if (y >= 0 && y < 64 && x >= 0 && x < 64) {
            acc = eb[o];
            for (int i = 0; i < 3; ++i) {
                const float* ip = inp + ((b * 3 + i) * 64) * 64;
                const float* wp = s_ew + (o * 3 + i) * 9;
                #pragma unroll
                for (int ky = 0; ky < 3; ++ky) {
                    int sy = y + ky - 1;
                    if (sy < 0 || sy > 63) continue;
                    #pragma unroll
                    for (int kx = 0; kx < 3; ++kx) {
                        int sx = x + kx - 1;
                        if (sx < 0 || sx > 63) continue;
                        acc += ip[sy * 64 + sx] * wp[ky * 3 + kx];
                    }
                }
            }
        }
        featpad[idx] = acc;
    } else if (bb < 2434) {
        // per-row prep + score MLP (2->256->1) folded with sb1
        int row = (bb - 2178) * 256 + tt0;
        int v = row & 3;
        int bq = row >> 2;
        int b = bq >> 13;
        float c0 = coord[bq * 2 + 0], c1 = coord[bq * 2 + 1];
        float s0 = scale[bq * 2 + 0], s1 = scale[bq * 2 + 1];
        float s00 = scale[(b * QN) * 2 + 0];
        float s01 = scale[(b * QN) * 2 + 1];
        float rx = (1.0f - s00) / 63.0f;
        float ry = (1.0f - s01) / 63.0f;
        float vx = (v & 2) ? 1.0f : -1.0f;
        float vy = (v & 1) ? 1.0f : -1.0f;
        float cc0 = c0 + vx * rx + 1e-6f;
        float cc1 = c1 + vy * ry + 1e-6f;
        cc0 = fminf(fmaxf(cc0, -1.0f + 1e-6f), 1.0f - 1e-6f);
        cc1 = fminf(fmaxf(cc1, -1.0f + 1e-6f), 1.0f - 1e-6f);
        int ih = (int)rintf((cc0 + 1.0f) * 32.0f - 0.5f);
        int iw = (int)rintf((cc1 + 1.0f) * 32.0f - 0.5f);
        ih = min(max(ih, 0), 63);
        iw = min(max(iw, 0), 63);
        float ck0 = (2.0f * (float)ih + 1.0f) / 64.0f - 1.0f;
        float ck1 = (2.0f * (float)iw + 1.0f) / 64.0f - 1.0f;
        float rel0 = (c0 - ck0) * 64.0f;
        float rel1 = (c1 - ck1) * 64.0f;
        mlp_in[row] = make_float4(rel0, rel1, s0 * 64.0f, s1 * 64.0f);
        ihiw[row] = make_int2(ih, iw);
        float sc = sb1[0];
        #pragma unroll 4
        for (int t2 = 0; t2 < 256; ++t2) {
            float h = gelu_f(fmaf(rel0, sw0[t2], fmaf(rel1, sw0[256 + t2], sb0[t2])));
            sc = fmaf(h, sw1[t2], sc);
        }
        scoreg[row] = sc;
    } else {
        // weight convert to LANE-MAJOR fragment layouts (coalesced loads in k_fused).
        int idx = (bb - 2434) * 256 + tt0;
        if (idx < 442368) {
            int j = idx & 7, ln = (idx >> 3) & 63, kf = (idx >> 9) & 7, tl = idx >> 12;
            int np = tl * 16 + (ln & 15);
            int kk = kf * 32 + (ln >> 4) * 8 + j;
            int k_out = np / 576;
            int rem = np - 576 * k_out;
            int tap = rem >> 6, cch = rem & 63;
            int n = (cch * 9 + tap) * 3 + k_out;
            w2tp[idx] = (_Float16)iw2[kk * 1728 + n];
            if (kf == 0 && j == 0 && (ln >> 4) == 0) b2p[np] = ib2[n];
        } else {
            int i2 = idx - 442368;
            int j = i2 & 7, ln = (i2 >> 3) & 63, kf = (i2 >> 9) & 7, ct = i2 >> 12;
            int col = ct * 16 + (ln & 15);
            int kk = kf * 32 + (ln >> 4) * 8 + j;
            w1tp[i2] = (_Float16)iw1[kk * 256 + col];
        }
    }
}

// ---------------- K_fused: h0 -> h1 (MFMA) -> GEMM3 + value-dot -> +score -> weight MLP
__global__ __launch_bounds__(256, 2) void k_fused(const float* __restrict__ featpad,
                                                  const float4* __restrict__ mlp_in,
                                                  const int2* __restrict__ ihiw,
                                                  const float* __restrict__ iw0,
                                                  const float* __restrict__ ib0,
                                                  const _Float16* __restrict__ w1tp,
                                                  const float* __restrict__ ib1,
                                                  const _Float16* __restrict__ w2tp,
                                                  const float* __restrict__ b2p,
                                                  const float* __restrict__ scoreg,
                                                  const float* __restrict__ ww0,
                                                  const float* __restrict__ wb0,
                                                  const float* __restrict__ ww1,
                                                  const float* __restrict__ wb1,
                                                  float* __restrict__ out) {
    // pool: s_valT [576][64] f16 row-XOR swizzled = 73728 B; aliased by s_h0/h1 [64][264] f16
    __shared__ __align__(16) char pool[576 * 64 * 2];
    _Float16* s_h0   = (_Float16*)pool;
    _Float16* s_valT = (_Float16*)pool;
    __shared__ float4 s_min[MR];
    __shared__ int    s_base[MR];
    __shared__ int    s_dtab[9];
    __shared__ float  s_pred[MR][3];
    __shared__ float  s_score[MR];
    __shared__ float  s_wred[48][4];

    const int t = threadIdx.x;
    const int wave = t >> 6, lane = t & 63, quad = lane >> 4, l15 = lane & 15;
    const int rowbase = blockIdx.x * MR;

    if (t < MR) {
        int row = rowbase + t;
        s_min[t] = mlp_in[row];
        s_score[t] = scoreg[row];
        int b = row >> 15;
        int2 p = ihiw[row];
        s_base[t] = ((b * 66 + p.x) * 66 + p.y) * 64;
    }
    if (t < 9) { int di = t / 3; s_dtab[t] = (di * 66 + (t - 3 * di)) * 64; }
    if (t < MR * 3) s_pred[t / 3][t % 3] = 0.0f;
    __syncthreads();

    // ---- h0 (4->256) fp32 VALU -> LDS f16 ([64][264])
    {
        float w0 = iw0[t], w1 = iw0[256 + t], w2 = iw0[512 + t], w3 = iw0[768 + t];
        float bb = ib0[t];
        #pragma unroll 4
        for (int r = 0; r < MR; ++r) {
            float4 m = s_min[r];
            s_h0[r * H0S + t] =
                (_Float16)gelu_f(fmaf(m.x, w0, fmaf(m.y, w1, fmaf(m.z, w2, fmaf(m.w, w3, bb)))));
        }
    }
    __syncthreads();

    // ---- preload h1 B first-half X(ct=wave*4): latency covered by the 32 ds_reads below
    f16x8 hX[4], hY[4];
    {
        const _Float16* wp = w1tp + (size_t)((wave * 4) * 8) * 512 + lane * 8;
        #pragma unroll
        for (int kf = 0; kf < 4; ++kf) hX[kf] = *(const f16x8*)(wp + kf * 512);
    }

    f16x8 a[4][8];   // A fragments: 4 row-tiles x 8 k-frags (whole 64xK for this wave)
    #pragma unroll
    for (int rt = 0; rt < 4; ++rt)
        #pragma unroll
        for (int kf = 0; kf < 8; ++kf)
            a[rt][kf] = *(const f16x8*)(s_h0 + (rt * 16 + l15) * H0S + kf * 32 + quad * 8);
    __syncthreads();   // all h0 reads done before in-place h1 writes

    // ---- h1 (256->256) MFMA, X/Y software pipeline; wave owns col-tiles wave*4..+3
    #pragma unroll 1
    for (int c = 0; c < 4; ++c) {
        int ct = wave * 4 + c;
        {   // load this tile's second half Y
            const _Float16* wp = w1tp + (size_t)(ct * 8 + 4) * 512 + lane * 8;
            #pragma unroll
            for (int kf = 0; kf < 4; ++kf) hY[kf] = *(const f16x8*)(wp + kf * 512);
        }
        f32x4 acc[4] = {{0.f,0.f,0.f,0.f},{0.f,0.f,0.f,0.f},{0.f,0.f,0.f,0.f},{0.f,0.f,0.f,0.f}};
        #pragma unroll
        for (int kf = 0; kf < 4; ++kf)
            #pragma unroll
            for (int rt = 0; rt < 4; ++rt)
                acc[rt] = __builtin_amdgcn_mfma_f32_16x16x32_f16(a[rt][kf], hX[kf], acc[rt], 0, 0, 0);
        if (c < 3) {   // prefetch next tile's first half X
            const _Float16* wp = w1tp + (size_t)((ct + 1) * 8) * 512 + lane * 8;
            #pragma unroll
            for (int kf = 0; kf < 4; ++kf) hX[kf] = *(const f16x8*)(wp + kf * 512);
        }
        #pragma unroll
        for (int kf = 0; kf < 4; ++kf)
            #pragma unroll
            for (int rt = 0; rt < 4; ++rt)
                acc[rt] = __builtin_amdgcn_mfma_f32_16x16x32_f16(a[rt][kf + 4], hY[kf], acc[rt], 0, 0, 0);
        int col = ct * 16 + l15;
        float bias = ib1[col];
        #pragma unroll
        for (int rt = 0; rt < 4; ++rt)
            #pragma unroll
            for (int reg = 0; reg < 4; ++reg)
                s_h0[(rt * 16 + quad * 4 + reg) * H0S + col] = (_Float16)gelu_f(acc[rt][reg] + bias);
    }
    __syncthreads();

    // ---- A3 fragments from LDS h1 (reuse a[])
    #pragma unroll
    for (int rt = 0; rt < 4; ++rt)
        #pragma unroll
        for (int kf = 0; kf < 8; ++kf)
            a[rt][kf] = *(const f16x8*)(s_h0 + (rt * 16 + l15) * H0S + kf * 32 + quad * 8);
    __syncthreads();   // h1 reads done; region becomes s_valT

    // ---- preload first GEMM3 B half-tile (latency hidden under gather)
    const int tbase = wave * 27;
    f16x8 bfX[4], bfY[4];
    {
        const _Float16* wp = w2tp + (size_t)(tbase * 8) * 512 + lane * 8;
        #pragma unroll
        for (int kf = 0; kf < 4; ++kf) bfX[kf] = *(const f16x8*)(wp + kf * 512);
    }

    // ---- value gather (round-5 pattern: lane = row, conflict-free LDS writes),
    //      batched 4 loads at a time so the L2/HBM latencies overlap
    #pragma unroll 1
    for (int g4 = 0; g4 < 9; ++g4) {
        float4 v[4];
        #pragma unroll
        for (int u = 0; u < 4; ++u) {
            int c4 = wave + (g4 * 4 + u) * 4;
            int tap = c4 >> 4;
            int cch0 = (c4 & 15) << 2;
            v[u] = *(const float4*)(featpad + s_base[lane] + s_dtab[tap] + cch0);
        }
        #pragma unroll
        for (int u = 0; u < 4; ++u) {
            int c4 = wave + (g4 * 4 + u) * 4;
            int cfp = c4 << 2;
            s_valT[(cfp + 0) * 64 + (lane ^ (((cfp + 0) & 7) << 3))] = (_Float16)v[u].x;
            s_valT[(cfp + 1) * 64 + (lane ^ (((cfp + 1) & 7) << 3))] = (_Float16)v[u].y;
            s_valT[(cfp + 2) * 64 + (lane ^ (((cfp + 2) & 7) << 3))] = (_Float16)v[u].z;
            s_valT[(cfp + 3) * 64 + (lane ^ (((cfp + 3) & 7) << 3))] = (_Float16)v[u].w;
        }
    }
    __syncthreads();

    // ---- GEMM3 (256->1728 permuted cols) + fused value-dot, X/Y pipelined B
    const int kt0 = tbase / 36;
    int bsplit = (kt0 + 1) * 36 - tbase; if (bsplit > 27) bsplit = 27;
    const int ktB = (tbase + 26) / 36;
    const int swz = (l15 & 7) << 3;

    float pA[4][4];
    #pragma unroll
    for (int rt = 0; rt < 4; ++rt)
        #pragma unroll
        for (int rg = 0; rg < 4; ++rg) pA[rt][rg] = 0.f;

    float bv;
    #pragma unroll 1
    for (int i = 0; i < 27; ++i) {
        int ti = tbase + i;
        {   // load current tile's second B half (Y) + bias
            const _Float16* wp = w2tp + (size_t)(ti * 8 + 4) * 512 + lane * 8;
            #pragma unroll
            for (int kf = 0; kf < 4; ++kf) bfY[kf] = *(const f16x8*)(wp + kf * 512);
            bv = b2p[ti * 16 + l15];
        }
        f32x4 acc[4] = {{0.f,0.f,0.f,0.f},{0.f,0.f,0.f,0.f},{0.f,0.f,0.f,0.f},{0.f,0.f,0.f,0.f}};
        #pragma unroll
        for (int kf = 0; kf < 4; ++kf)
            #pragma unroll
            for (int rt = 0; rt < 4; ++rt)
                acc[rt] = __builtin_amdgcn_mfma_f32_16x16x32_f16(a[rt][kf], bfX[kf], acc[rt], 0, 0, 0);
        if (i < 26) {   // prefetch next tile's first B half (X)
            const _Float16* wp = w2tp + (size_t)((ti + 1) * 8) * 512 + lane * 8;
            #pragma unroll
            for (int kf = 0; kf < 4; ++kf) bfX[kf] = *(const f16x8*)(wp + kf * 512);
        }
        #pragma unroll
        for (int kf = 0; kf < 4; ++kf)
            #pragma unroll
            for (int rt = 0; rt < 4; ++rt)
                acc[rt] = __builtin_amdgcn_mfma_f32_16x16x32_f16(a[rt][kf + 4], bfY[kf], acc[rt], 0, 0, 0);
        // epilogue: fold (acc + bias) * val into pA
        int cf36 = ti - (ti / 36) * 36;
        int cfp = cf36 * 16 + l15;
        const _Float16* vbase = s_valT + cfp * 64;
        #pragma unroll
        for (int rt = 0; rt < 4; ++rt) {
            f16x4 vv = *(const f16x4*)(vbase + ((rt * 16 + quad * 4) ^ swz));
            #pragma unroll
            for (int rg = 0; rg < 4; ++rg) {
                float s = acc[rt][rg] + bv;
                pA[rt][rg] = fmaf(s, (float)vv[rg], pA[rt][rg]);
            }
        }
        if (i == bsplit - 1) {   // wave-uniform flush into s_pred[*][kt0]
            #pragma unroll
            for (int rt = 0; rt < 4; ++rt)
                #pragma unroll
                for (int rg = 0; rg < 4; ++rg) {
                    float x = pA[rt][rg];
                    #pragma unroll
                    for (int m = 1; m < 16; m <<= 1) x += __shfl_xor(x, m, 64);
                    if (l15 == 0) atomicAdd(&s_pred[rt * 16 + quad * 4 + rg][kt0], x);
                    pA[rt][rg] = 0.f;
                }
        }
    }
    // final flush into s_pred[*][ktB]
    #pragma unroll
    for (int rt = 0; rt < 4; ++rt)
        #pragma unroll
        for (int rg = 0; rg < 4; ++rg) {
            float x = pA[rt][rg];
            #pragma unroll
            for (int m = 1; m < 16; m <<= 1) x += __shfl_xor(x, m, 64);
            if (l15 == 0) atomicAdd(&s_pred[rt * 16 + quad * 4 + rg][ktB], x);
        }
    __syncthreads();

    // ---- fused weight MLP (4->256->1): 16 bq x 3 k outputs, 4 sub-threads each
    if (t < 192) {
        int o = t >> 2, sub = t & 3;          // o = bql*3 + k
        int bql = o / 3, k = o - 3 * bql;
        float x0 = s_pred[bql * 4 + 0][k] + s_score[bql * 4 + 0];
        float x1 = s_pred[bql * 4 + 1][k] + s_score[bql * 4 + 1];
        float x2 = s_pred[bql * 4 + 2][k] + s_score[bql * 4 + 2];
        float x3 = s_pred[bql * 4 + 3][k] + s_score[bql * 4 + 3];
        float acc = 0.0f;
        int j0 = sub * 64;
        #pragma unroll 4
        for (int j = j0; j < j0 + 64; ++j) {
            float h = gelu_f(fmaf(x0, ww0[j], fmaf(x1, ww0[256 + j],
                          fmaf(x2, ww0[512 + j], fmaf(x3, ww0[768 + j], wb0[j])))));
            acc = fmaf(h, ww1[j], acc);
        }
        s_wred[o][sub] = acc;
    }
    __syncthreads();
    if (t < 48) {
        int bql = t / 3, k = t - 3 * bql;
        float r2 = s_wred[t][0] + s_wred[t][1] + s_wred[t][2] + s_wred[t][3] + wb1[0];
        out[(blockIdx.x * 16 + bql) * 3 + k] = r2;
    }
}

extern "C" void kernel_launch(void* const* d_in, const int* in_sizes, int n_in,
                              void* d_out, int out_size, void* d_ws, size_t ws_size,
                              hipStream_t stream) {
    const float* inp   = (const float*)d_in[0];
    const float* coord = (const float*)d_in[1];
    const float* scale = (const float*)d_in[2];
    const float* ew    = (const float*)d_in[3];
    const float* eb    = (const float*)d_in[4];
    const float* iw0   = (const float*)d_in[5];
    const float* ib0   = (const float*)d_in[6];
    const float* iw1   = (const float*)d_in[7];
    const float* ib1   = (const float*)d_in[8];
    const float* iw2   = (const float*)d_in[9];
    const float* ib2   = (const float*)d_in[10];
    const float* sw0   = (const float*)d_in[11];
    const float* sb0   = (const float*)d_in[12];
    const float* sw1   = (const float*)d_in[13];
    const float* sb1   = (const float*)d_in[14];
    const float* ww0   = (const float*)d_in[15];
    const float* wb0   = (const float*)d_in[16];
    const float* ww1   = (const float*)d_in[17];
    const float* wb1   = (const float*)d_in[18];
    float* out = (float*)d_out;

    char* ws = (char*)d_ws;
    float*     featpad = (float*)(ws + 0);           // 2,230,272
    float4*    mlp_in  = (float4*)(ws + 2230272);    // 1,048,576
    int2*      ihiw    = (int2*)(ws + 3278848);      //   524,288
    float*     scoreg  = (float*)(ws + 3803136);     //   262,144
    _Float16*  w1tp    = (_Float16*)(ws + 4065280);  //   131,072
    _Float16*  w2tp    = (_Float16*)(ws + 4196352);  //   884,736
    float*     b2p     = (float*)(ws + 5081088);     //     6,912  (end 5,088,000)

    k_pre<<<dim3(4418), dim3(256), 0, stream>>>(inp, ew, eb, coord, scale,
                                                sw0, sb0, sw1, sb1, iw1, iw2, ib2,
                                                featpad, mlp_in, ihiw, scoreg,
                                                w1tp, w2tp, b2p);
    k_fused<<<dim3(NBLK), dim3(256), 0, stream>>>(featpad, mlp_in, ihiw,
                                                  iw0, ib0, w1tp, ib1, w2tp, b2p,
                                                  scoreg, ww0, wb0, ww1, wb1, out);
}

// Round 8
// 231.876 us; speedup vs baseline: 1.0834x; 1.0368x over previous
//
#include <hip/hip_runtime.h>

#define QN 8192
#define CCH 64
#define NROW 65536   // B*Q*4
#define MR 64        // rows per block in k_fused
#define NBLK (NROW / MR)   // 1024
#define H0S 264      // LDS f16 stride for h0/h1 staging

typedef _Float16 f16x8 __attribute__((ext_vector_type(8)));
typedef _Float16 f16x4 __attribute__((ext_vector_type(4)));
typedef float f32x4 __attribute__((ext_vector_type(4)));

__device__ __forceinline__ float gelu_f(float x) {
    float x2 = x * x;
    float tt = fmaf(0.044715f, x2, 1.0f);
    float e = __expf(1.5957691216f * x * tt);
    float r = __builtin_amdgcn_rcpf(1.0f + e);
    return x - x * r;
}

// ---------------- K_pre: conv (blocks 0..2177) + prep (2178..2433) + cvt (2434..4417)
__global__ __launch_bounds__(256) void k_pre(const float* __restrict__ inp,
                                             const float* __restrict__ ew,
                                             const float* __restrict__ eb,
                                             const float* __restrict__ coord,
                                             const float* __restrict__ scale,
                                             const float* __restrict__ sw0,
                                             const float* __restrict__ sb0,
                                             const float* __restrict__ sw1,
                                             const float* __restrict__ sb1,
                                             const float* __restrict__ iw1,
                                             const float* __restrict__ iw2,
                                             const float* __restrict__ ib2,
                                             float* __restrict__ featpad,
                                             float4* __restrict__ mlp_in,
                                             int2* __restrict__ ihiw,
                                             float* __restrict__ scoreg,
                                             _Float16* __restrict__ w1tp,
                                             _Float16* __restrict__ w2tp,
                                             float* __restrict__ b2p) {
    const int bb = blockIdx.x;
    const int tt0 = threadIdx.x;
    if (bb < 2178) {
        __shared__ float s_ew[1728];
        for (int i = tt0; i < 1728; i += 256) s_ew[i] = ew[i];
        __syncthreads();
        int idx = bb * 256 + tt0;
        const int total = 2 * 66 * 66 * CCH;
        if (idx >= total) return;
        int o = idx & 63; int pix = idx >> 6;
        int xx = pix % 66; int t2 = pix / 66;
        int yy = t2 % 66;  int b = t2 / 66;
        int y = yy - 1, x = xx - 1;
        float acc = 0.0f;
        if (y >= 0 && y < 64 && x >= 0 && x < 64) {
            acc = eb[o];
            for (int i = 0; i < 3; ++i) {
                const float* ip = inp + ((b * 3 + i) * 64) * 64;
                const float* wp = s_ew + (o * 3 + i) * 9;
                #pragma unroll
                for (int ky = 0; ky < 3; ++ky) {
                    int sy = y + ky - 1;
                    if (sy < 0 || sy > 63) continue;
                    #pragma unroll
                    for (int kx = 0; kx < 3; ++kx) {
                        int sx = x + kx - 1;
                        if (sx < 0 || sx > 63) continue;
                        acc += ip[sy * 64 + sx] * wp[ky * 3 + kx];
                    }
                }
            }
        }
        featpad[idx] = acc;
    } else if (bb < 2434) {
        int row = (bb - 2178) * 256 + tt0;
        int v = row & 3;
        int bq = row >> 2;
        int b = bq >> 13;
        float c0 = coord[bq * 2 + 0], c1 = coord[bq * 2 + 1];
        float s0 = scale[bq * 2 + 0], s1 = scale[bq * 2 + 1];
        float s00 = scale[(b * QN) * 2 + 0];
        float s01 = scale[(b * QN) * 2 + 1];
        float rx = (1.0f - s00) / 63.0f;
        float ry = (1.0f - s01) / 63.0f;
        float vx = (v & 2) ? 1.0f : -1.0f;
        float vy = (v & 1) ? 1.0f : -1.0f;
        float cc0 = c0 + vx * rx + 1e-6f;
        float cc1 = c1 + vy * ry + 1e-6f;
        cc0 = fminf(fmaxf(cc0, -1.0f + 1e-6f), 1.0f - 1e-6f);
        cc1 = fminf(fmaxf(cc1, -1.0f + 1e-6f), 1.0f - 1e-6f);
        int ih = (int)rintf((cc0 + 1.0f) * 32.0f - 0.5f);
        int iw = (int)rintf((cc1 + 1.0f) * 32.0f - 0.5f);
        ih = min(max(ih, 0), 63);
        iw = min(max(iw, 0), 63);
        float ck0 = (2.0f * (float)ih + 1.0f) / 64.0f - 1.0f;
        float ck1 = (2.0f * (float)iw + 1.0f) / 64.0f - 1.0f;
        float rel0 = (c0 - ck0) * 64.0f;
        float rel1 = (c1 - ck1) * 64.0f;
        mlp_in[row] = make_float4(rel0, rel1, s0 * 64.0f, s1 * 64.0f);
        ihiw[row] = make_int2(ih, iw);
        float sc = sb1[0];
        #pragma unroll 4
        for (int t2 = 0; t2 < 256; ++t2) {
            float h = gelu_f(fmaf(rel0, sw0[t2], fmaf(rel1, sw0[256 + t2], sb0[t2])));
            sc = fmaf(h, sw1[t2], sc);
        }
        scoreg[row] = sc;
    } else {
        // weight convert to LANE-MAJOR fragment layouts (coalesced loads in k_fused).
        int idx = (bb - 2434) * 256 + tt0;
        if (idx < 442368) {
            int j = idx & 7, ln = (idx >> 3) & 63, kf = (idx >> 9) & 7, tl = idx >> 12;
            int np = tl * 16 + (ln & 15);
            int kk = kf * 32 + (ln >> 4) * 8 + j;
            int k_out = np / 576;
            int rem = np - 576 * k_out;
            int tap = rem >> 6, cch = rem & 63;
            int n = (cch * 9 + tap) * 3 + k_out;
            w2tp[idx] = (_Float16)iw2[kk * 1728 + n];
            if (kf == 0 && j == 0 && (ln >> 4) == 0) b2p[np] = ib2[n];
        } else {
            int i2 = idx - 442368;
            int j = i2 & 7, ln = (i2 >> 3) & 63, kf = (i2 >> 9) & 7, ct = i2 >> 12;
            int col = ct * 16 + (ln & 15);
            int kk = kf * 32 + (ln >> 4) * 8 + j;
            w1tp[i2] = (_Float16)iw1[kk * 256 + col];
        }
    }
}

// ---- macros for k_fused pipelines
#define LDX1(B, CT) do { const _Float16* wp_ = w1tp + (size_t)((CT) * 8) * 512 + lane * 8;        \
    _Pragma("unroll") for (int kf_ = 0; kf_ < 4; ++kf_) B[kf_] = *(const f16x8*)(wp_ + kf_ * 512); } while (0)
#define LDY1(B, CT) do { const _Float16* wp_ = w1tp + (size_t)((CT) * 8 + 4) * 512 + lane * 8;    \
    _Pragma("unroll") for (int kf_ = 0; kf_ < 4; ++kf_) B[kf_] = *(const f16x8*)(wp_ + kf_ * 512); } while (0)
#define LDX2(B, TI) do { const _Float16* wp_ = w2tp + (size_t)((TI) * 8) * 512 + lane * 8;        \
    _Pragma("unroll") for (int kf_ = 0; kf_ < 4; ++kf_) B[kf_] = *(const f16x8*)(wp_ + kf_ * 512); } while (0)
#define LDY2(B, BV, TI) do { const _Float16* wp_ = w2tp + (size_t)((TI) * 8 + 4) * 512 + lane * 8;\
    _Pragma("unroll") for (int kf_ = 0; kf_ < 4; ++kf_) B[kf_] = *(const f16x8*)(wp_ + kf_ * 512);\
    BV = b2p[(TI) * 16 + l15]; } while (0)
#define ZACC() do { _Pragma("unroll") for (int rt_ = 0; rt_ < 4; ++rt_)                           \
    acc[rt_] = (f32x4){0.f, 0.f, 0.f, 0.f}; } while (0)
#define MFMAH(B, OFS) do { _Pragma("unroll") for (int kf_ = 0; kf_ < 4; ++kf_)                    \
    { _Pragma("unroll") for (int rt_ = 0; rt_ < 4; ++rt_)                                         \
      acc[rt_] = __builtin_amdgcn_mfma_f32_16x16x32_f16(a[rt_][kf_ + (OFS)], B[kf_], acc[rt_], 0, 0, 0); } } while (0)
#define H1EPI(CT) do { int col_ = (CT) * 16 + l15; float bias_ = ib1[col_];                       \
    _Pragma("unroll") for (int rt_ = 0; rt_ < 4; ++rt_)                                           \
      { _Pragma("unroll") for (int rg_ = 0; rg_ < 4; ++rg_)                                       \
        s_h0[(rt_ * 16 + quad * 4 + rg_) * H0S + col_] = (_Float16)gelu_f(acc[rt_][rg_] + bias_); } } while (0)
#define EPI3(TI, BV) do { int cf36_ = (TI) - ((TI) / 36) * 36;                                    \
    const _Float16* vb_ = s_valT + (cf36_ * 16 + l15) * 64;                                       \
    _Pragma("unroll") for (int rt_ = 0; rt_ < 4; ++rt_) {                                         \
      f16x4 vv_ = *(const f16x4*)(vb_ + ((rt_ * 16 + quad * 4) ^ swz));                           \
      _Pragma("unroll") for (int rg_ = 0; rg_ < 4; ++rg_)                                         \
        pA[rt_][rg_] = fmaf(acc[rt_][rg_] + (BV), (float)vv_[rg_], pA[rt_][rg_]); } } while (0)
#define FLUSH(KT) do { _Pragma("unroll") for (int rt_ = 0; rt_ < 4; ++rt_)                        \
    { _Pragma("unroll") for (int rg_ = 0; rg_ < 4; ++rg_) {                                       \
        float x_ = pA[rt_][rg_];                                                                  \
        _Pragma("unroll") for (int m_ = 1; m_ < 16; m_ <<= 1) x_ += __shfl_xor(x_, m_, 64);       \
        if (l15 == 0) atomicAdd(&s_pred[rt_ * 16 + quad * 4 + rg_][KT], x_);                      \
        pA[rt_][rg_] = 0.f; } } } while (0)

// ---------------- K_fused: h0 -> h1 (MFMA) -> GEMM3 + value-dot -> +score -> weight MLP
__global__ __launch_bounds__(256, 2) void k_fused(const float* __restrict__ featpad,
                                                  const float4* __restrict__ mlp_in,
                                                  const int2* __restrict__ ihiw,
                                                  const float* __restrict__ iw0,
                                                  const float* __restrict__ ib0,
                                                  const _Float16* __restrict__ w1tp,
                                                  const float* __restrict__ ib1,
                                                  const _Float16* __restrict__ w2tp,
                                                  const float* __restrict__ b2p,
                                                  const float* __restrict__ scoreg,
                                                  const float* __restrict__ ww0,
                                                  const float* __restrict__ wb0,
                                                  const float* __restrict__ ww1,
                                                  const float* __restrict__ wb1,
                                                  float* __restrict__ out) {
    // pool: s_valT [576][64] f16 row-XOR swizzled = 73728 B; aliased by s_h0/h1 [64][264] f16
    __shared__ __align__(16) char pool[576 * 64 * 2];
    _Float16* s_h0   = (_Float16*)pool;
    _Float16* s_valT = (_Float16*)pool;
    __shared__ float4 s_min[MR];
    __shared__ int    s_base[MR];
    __shared__ int    s_dtab[9];
    __shared__ float  s_pred[MR][3];
    __shared__ float  s_score[MR];
    __shared__ float  s_wred[48][4];

    const int t = threadIdx.x;
    const int wave = t >> 6, lane = t & 63, quad = lane >> 4, l15 = lane & 15;
    const int rowbase = blockIdx.x * MR;

    if (t < MR) {
        int row = rowbase + t;
        s_min[t] = mlp_in[row];
        s_score[t] = scoreg[row];
        int b = row >> 15;
        int2 p = ihiw[row];
        s_base[t] = ((b * 66 + p.x) * 66 + p.y) * 64;
    }
    if (t < 9) { int di = t / 3; s_dtab[t] = (di * 66 + (t - 3 * di)) * 64; }
    if (t < MR * 3) s_pred[t / 3][t % 3] = 0.0f;
    __syncthreads();

    // ---- h0 (4->256) fp32 VALU -> LDS f16 ([64][264])
    {
        float w0 = iw0[t], w1 = iw0[256 + t], w2 = iw0[512 + t], w3 = iw0[768 + t];
        float bb = ib0[t];
        #pragma unroll 4
        for (int r = 0; r < MR; ++r) {
            float4 m = s_min[r];
            s_h0[r * H0S + t] =
                (_Float16)gelu_f(fmaf(m.x, w0, fmaf(m.y, w1, fmaf(m.z, w2, fmaf(m.w, w3, bb)))));
        }
    }
    __syncthreads();

    // ---- shared B double-buffers (serve h1 AND GEMM3 prologue)
    f16x8 bX0[4], bX1[4], bY0[4], bY1[4];
    float bv0, bv1;
    f32x4 acc[4];
    const int w4 = wave * 4;
    const int tbase = wave * 27;

    // preload h1 tiles: X(w4), Y(w4), X(w4+1) — latency covered by 32 ds_reads below
    LDX1(bX0, w4);
    LDY1(bY0, w4);
    LDX1(bX1, w4 + 1);

    f16x8 a[4][8];   // A fragments: 4 row-tiles x 8 k-frags (whole 64xK for this wave)
    #pragma unroll
    for (int rt = 0; rt < 4; ++rt)
        #pragma unroll
        for (int kf = 0; kf < 8; ++kf)
            a[rt][kf] = *(const f16x8*)(s_h0 + (rt * 16 + l15) * H0S + kf * 32 + quad * 8);
    __syncthreads();   // all h0 reads done before in-place h1 writes

    // ---- h1 (256->256) MFMA, deep-pipelined; GEMM3 preloads slotted into the tail
    // c=0
    LDY1(bY1, w4 + 1);
    ZACC(); MFMAH(bX0, 0);
    LDX1(bX0, w4 + 2);
    MFMAH(bY0, 4);
    H1EPI(w4);
    // c=1
    LDY1(bY0, w4 + 2);
    ZACC(); MFMAH(bX1, 0);
    LDX1(bX1, w4 + 3);
    MFMAH(bY1, 4);
    H1EPI(w4 + 1);
    // c=2  (prefetch GEMM3 X(tbase) into freed bX0)
    LDY1(bY1, w4 + 3);
    ZACC(); MFMAH(bX0, 0);
    LDX2(bX0, tbase);
    MFMAH(bY0, 4);
    H1EPI(w4 + 2);
    // c=3  (prefetch GEMM3 Y(tbase), X(tbase+1))
    LDY2(bY0, bv0, tbase);
    ZACC(); MFMAH(bX1, 0);
    LDX2(bX1, tbase + 1);
    MFMAH(bY1, 4);
    H1EPI(w4 + 3);
    __syncthreads();

    // ---- A3 fragments from LDS h1 (reuse a[])
    #pragma unroll
    for (int rt = 0; rt < 4; ++rt)
        #pragma unroll
        for (int kf = 0; kf < 8; ++kf)
            a[rt][kf] = *(const f16x8*)(s_h0 + (rt * 16 + l15) * H0S + kf * 32 + quad * 8);
    __syncthreads();   // h1 reads done; region becomes s_valT

    // ---- value gather (lane = row, conflict-free LDS writes), batched 4 loads
    #pragma unroll 1
    for (int g4 = 0; g4 < 9; ++g4) {
        float4 v[4];
        #pragma unroll
        for (int u = 0; u < 4; ++u) {
            int c4 = wave + (g4 * 4 + u) * 4;
            int tap = c4 >> 4;
            int cch0 = (c4 & 15) << 2;
            v[u] = *(const float4*)(featpad + s_base[lane] + s_dtab[tap] + cch0);
        }
        #pragma unroll
        for (int u = 0; u < 4; ++u) {
            int c4 = wave + (g4 * 4 + u) * 4;
            int cfp = c4 << 2;
            s_valT[(cfp + 0) * 64 + (lane ^ (((cfp + 0) & 7) << 3))] = (_Float16)v[u].x;
            s_valT[(cfp + 1) * 64 + (lane ^ (((cfp + 1) & 7) << 3))] = (_Float16)v[u].y;
            s_valT[(cfp + 2) * 64 + (lane ^ (((cfp + 2) & 7) << 3))] = (_Float16)v[u].z;
            s_valT[(cfp + 3) * 64 + (lane ^ (((cfp + 3) & 7) << 3))] = (_Float16)v[u].w;
        }
    }
    __syncthreads();

    // ---- GEMM3 (256->1728 permuted cols) + fused value-dot, 2-tile-lookahead pipeline
    const int kt0 = tbase / 36;
    int bsplit = (kt0 + 1) * 36 - tbase; if (bsplit > 27) bsplit = 27;
    const int ktB = (tbase + 26) / 36;
    const int swz = (l15 & 7) << 3;

    float pA[4][4];
    #pragma unroll
    for (int rt = 0; rt < 4; ++rt)
        #pragma unroll
        for (int rg = 0; rg < 4; ++rg) pA[rt][rg] = 0.f;

    #pragma unroll 1
    for (int p = 0; p < 13; ++p) {
        int i = 2 * p;
        int ti = tbase + i;
        // even tile (bX0/bY0/bv0)
        LDY2(bY1, bv1, ti + 1);
        ZACC(); MFMAH(bX0, 0);
        LDX2(bX0, ti + 2);
        MFMAH(bY0, 4);
        EPI3(ti, bv0);
        if (i == bsplit - 1) FLUSH(kt0);
        // odd tile (bX1/bY1/bv1)
        LDY2(bY0, bv0, ti + 2);
        ZACC(); MFMAH(bX1, 0);
        if (p < 12) LDX2(bX1, ti + 3);
        MFMAH(bY1, 4);
        EPI3(ti + 1, bv1);
        if (i + 1 == bsplit - 1) FLUSH(kt0);
    }
    {   // tail tile tbase+26 (bX0/bY0/bv0)
        ZACC(); MFMAH(bX0, 0); MFMAH(bY0, 4);
        EPI3(tbase + 26, bv0);
        if (26 == bsplit - 1) FLUSH(kt0);
    }
    FLUSH(ktB);
    __syncthreads();

    // ---- fused weight MLP (4->256->1): 16 bq x 3 k outputs, 4 sub-threads each
    if (t < 192) {
        int o = t >> 2, sub = t & 3;          // o = bql*3 + k
        int bql = o / 3, k = o - 3 * bql;
        float x0 = s_pred[bql * 4 + 0][k] + s_score[bql * 4 + 0];
        float x1 = s_pred[bql * 4 + 1][k] + s_score[bql * 4 + 1];
        float x2 = s_pred[bql * 4 + 2][k] + s_score[bql * 4 + 2];
        float x3 = s_pred[bql * 4 + 3][k] + s_score[bql * 4 + 3];
        float acc2 = 0.0f;
        int j0 = sub * 64;
        #pragma unroll 4
        for (int j = j0; j < j0 + 64; ++j) {
            float h = gelu_f(fmaf(x0, ww0[j], fmaf(x1, ww0[256 + j],
                          fmaf(x2, ww0[512 + j], fmaf(x3, ww0[768 + j], wb0[j])))));
            acc2 = fmaf(h, ww1[j], acc2);
        }
        s_wred[o][sub] = acc2;
    }
    __syncthreads();
    if (t < 48) {
        int bql = t / 3, k = t - 3 * bql;
        float r2 = s_wred[t][0] + s_wred[t][1] + s_wred[t][2] + s_wred[t][3] + wb1[0];
        out[(blockIdx.x * 16 + bql) * 3 + k] = r2;
    }
}

extern "C" void kernel_launch(void* const* d_in, const int* in_sizes, int n_in,
                              void* d_out, int out_size, void* d_ws, size_t ws_size,
                              hipStream_t stream) {
    const float* inp   = (const float*)d_in[0];
    const float* coord = (const float*)d_in[1];
    const float* scale = (const float*)d_in[2];
    const float* ew    = (const float*)d_in[3];
    const float* eb    = (const float*)d_in[4];
    const float* iw0   = (const float*)d_in[5];
    const float* ib0   = (const float*)d_in[6];
    const float* iw1   = (const float*)d_in[7];
    const float* ib1   = (const float*)d_in[8];
    const float* iw2   = (const float*)d_in[9];
    const float* ib2   = (const float*)d_in[10];
    const float* sw0   = (const float*)d_in[11];
    const float* sb0   = (const float*)d_in[12];
    const float* sw1   = (const float*)d_in[13];
    const float* sb1   = (const float*)d_in[14];
    const float* ww0   = (const float*)d_in[15];
    const float* wb0   = (const float*)d_in[16];
    const float* ww1   = (const float*)d_in[17];
    const float* wb1   = (const float*)d_in[18];
    float* out = (float*)d_out;

    char* ws = (char*)d_ws;
    float*     featpad = (float*)(ws + 0);           // 2,230,272
    float4*    mlp_in  = (float4*)(ws + 2230272);    // 1,048,576
    int2*      ihiw    = (int2*)(ws + 3278848);      //   524,288
    float*     scoreg  = (float*)(ws + 3803136);     //   262,144
    _Float16*  w1tp    = (_Float16*)(ws + 4065280);  //   131,072
    _Float16*  w2tp    = (_Float16*)(ws + 4196352);  //   884,736
    float*     b2p     = (float*)(ws + 5081088);     //     6,912  (end 5,088,000)

    k_pre<<<dim3(4418), dim3(256), 0, stream>>>(inp, ew, eb, coord, scale,
                                                sw0, sb0, sw1, sb1, iw1, iw2, ib2,
                                                featpad, mlp_in, ihiw, scoreg,
                                                w1tp, w2tp, b2p);
    k_fused<<<dim3(NBLK), dim3(256), 0, stream>>>(featpad, mlp_in, ihiw,
                                                  iw0, ib0, w1tp, ib1, w2tp, b2p,
                                                  scoreg, ww0, wb0, ww1, wb1, out);
}